// Round 1
// 285.826 us; speedup vs baseline: 1.2021x; 1.2021x over previous
//
#include <hip/hip_runtime.h>
#include <hip/hip_fp16.h>
#include <math.h>

// Problem constants
#define NCH 72            // total channels (8*1 + 8*3 + 8*5)
#define SP  32768         // 32^3 spatial
#define NBATCH 8
#define NTOT (NBATCH*SP)  // per-channel element count = 262144

// ws layout (float offsets for the small stuff)
#define WS_SUMX   0       // 72
#define WS_SUMSQ  72      // 72
#define WS_SCALE  144     // 72 (per input channel inverse-std)
#define WS_BIAS   216     // 72
#define WS_K      288     // fp16 kernel matrix, fragment-blocked: 315 blocks * 1024 B

// byte offsets / strides for the packed fp16 x tensor
#define WS_XH_BYTES 323712          // 288*4 + 322560, 16B aligned
#define XH_ROW   2720               // 34 x-slots * 80 ci  (elements)
#define XH_PLANE 87040              // 32 * XH_ROW
#define XH_BATCH 2785280            // 32 * XH_PLANE

typedef __attribute__((ext_vector_type(8))) _Float16 half8;
typedef __attribute__((ext_vector_type(4))) float float4v;
typedef __attribute__((ext_vector_type(4))) int int4v;

__device__ __forceinline__ void chmap(int c, int& f, int& m, int& d, int& dim) {
  if (c < 8)       { f = 0; m = c;          d = 0;          dim = 1; }
  else if (c < 32) { f = 1; m = (c - 8)/3;  d = (c - 8)%3;  dim = 3; }
  else             { f = 2; m = (c - 32)/5; d = (c - 32)%5; dim = 5; }
}

// ---------------- prepack: x -> fp16 [b][z][y][x(34)][ci(80)] + fused BN stats ----------
// grid (64, 8): blockIdx.x = z*2 + half; block = half a z-plane (2 chunks of 256 pos)
__global__ __launch_bounds__(256) void prepack_kernel(const float* __restrict__ x,
                                                      float* __restrict__ ws) {
  __shared__ __align__(16) short tile[256 * 88];   // [pos(256)][ci(88 pad)] = 45 KB
  __shared__ float segS[72][3], segQ[72][3];
  const int t    = threadIdx.x;
  const int z    = blockIdx.x >> 1;
  const int half = blockIdx.x & 1;
  const int b    = blockIdx.y;
  ushort* xh = (ushort*)((char*)ws + WS_XH_BYTES);
  const float* xb = x + (size_t)b * NCH * SP + z * 1024 + half * 512;

  const int ci_s = t % 72, seg = t / 72;   // stats mapping (t < 216)
  float accS = 0.f, accQ = 0.f;

  // zero the ci pad (72..79) once: phase 2a copies it into the packed tensor, and
  // the conv multiplies it by B=0 -- stale LDS Inf/NaN would make 0*Inf = NaN.
  *(int4v*)&tile[t * 88 + 72] = (int4v){0, 0, 0, 0};

  for (int c = 0; c < 2; ++c) {
    if (c) __syncthreads();                 // protect tile reuse
    // phase 1: coalesced fp32 loads (fully unrolled -> deep MLP), short4 LDS writes
    #pragma unroll
    for (int cig = 0; cig < 18; ++cig) {
      float v0 = xb[(size_t)(cig*4 + 0) * SP + c * 256 + t];
      float v1 = xb[(size_t)(cig*4 + 1) * SP + c * 256 + t];
      float v2 = xb[(size_t)(cig*4 + 2) * SP + c * 256 + t];
      float v3 = xb[(size_t)(cig*4 + 3) * SP + c * 256 + t];
      short s4[4] = { (short)__half_as_short(__float2half(v0)),
                      (short)__half_as_short(__float2half(v1)),
                      (short)__half_as_short(__float2half(v2)),
                      (short)__half_as_short(__float2half(v3)) };
      *(int2*)&tile[t * 88 + cig * 4] = *(const int2*)s4;   // 8B aligned
    }
    __syncthreads();
    // phase 2a: coalesced writeout — 2560 16B segments (10 per pos), consecutive lanes
    {
      ushort* gb = xh + (size_t)b * XH_BATCH + (size_t)(z * 32 + (half * 2 + c) * 8) * XH_ROW;
      #pragma unroll
      for (int j = 0; j < 10; ++j) {
        const int s   = t + j * 256;        // 0..2559
        const int pos = s / 10, part = s - pos * 10;
        const int4v v = *(const int4v*)&tile[pos * 88 + part * 8];
        const int row = pos >> 5, xx = pos & 31;
        *(int4v*)(gb + (size_t)row * XH_ROW + xx * 80 + part * 8) = v;
      }
    }
    // phase 2b: stats from the tile (per-ci column sums)
    if (seg < 3) {
      const int p0 = seg * 86;
      const int pn = (seg == 2) ? 84 : 86;
      for (int i = 0; i < pn; ++i) {
        const float v = __half2float(__short_as_half(tile[(p0 + i) * 88 + ci_s]));
        accS += v; accQ += v * v;
      }
    }
  }
  if (seg < 3) { segS[ci_s][seg] = accS; segQ[ci_s][seg] = accQ; }
  __syncthreads();
  if (t < 144) {
    const int which = t / 72, ci = t % 72;
    const float v = which ? (segQ[ci][0] + segQ[ci][1] + segQ[ci][2])
                          : (segS[ci][0] + segS[ci][1] + segS[ci][2]);
    atomicAdd(&ws[(which ? WS_SUMSQ : WS_SUMX) + ci], v);
  }
}

// ---------------- finalize: scales, means -> bias ----------------
__global__ __launch_bounds__(128) void finalize_kernel(const float* __restrict__ weight,
                                                       const float* __restrict__ basis00,
                                                       float* __restrict__ ws) {
  __shared__ float s_mean[8], s_scale[8];
  const int c = threadIdx.x;
  const float invN = 1.0f / (float)NTOT;
  if (c < NCH) {
    float norm;
    if (c < 8) {
      float m = ws[WS_SUMX + c] * invN;
      norm = ws[WS_SUMSQ + c] * invN - m * m;
      s_mean[c] = m;
    } else if (c < 32) {
      int m0 = 8 + ((c - 8) / 3) * 3;
      norm = (ws[WS_SUMSQ+m0] + ws[WS_SUMSQ+m0+1] + ws[WS_SUMSQ+m0+2]) * invN;
    } else {
      int m0 = 32 + ((c - 32) / 5) * 5;
      norm = (ws[WS_SUMSQ+m0] + ws[WS_SUMSQ+m0+1] + ws[WS_SUMSQ+m0+2]
            + ws[WS_SUMSQ+m0+3] + ws[WS_SUMSQ+m0+4]) * invN;
    }
    float sc = 1.0f / sqrtf(norm + 1e-5f);
    ws[WS_SCALE + c] = sc;
    if (c < 8) s_scale[c] = sc;
  }
  __syncthreads();
  if (c < NCH) {
    float bia = 0.f;
    if (c < 8) {
      float id0 = 0.f, id1 = 0.f;
      #pragma unroll
      for (int t = 0; t < 27; ++t) { id0 += basis00[t]; id1 += basis00[27 + t]; }
      #pragma unroll
      for (int v = 0; v < 8; ++v) {
        float s  = s_scale[v];
        float w0 = weight[(c*8 + v)*2 + 0] * s;
        float w1 = weight[(c*8 + v)*2 + 1] * s;
        bia -= (w0 * id0 + w1 * id1) * s_mean[v];
      }
    }
    ws[WS_BIAS + c] = bia;
  }
}

// ---------------- build fp16 kernel matrix, fragment-blocked layout ----------------
// 315 blocks of 1024 B: block = tap*35 + kc*5 + cj; element e: lane l = e/8, j = e%8;
// co = cj*16 + (l&15);  kk = kc*32 + (l>>4)*8 + j  (zero for co>=72 or kk>=216)
__global__ __launch_bounds__(256) void build_half_kernel(const float* __restrict__ weight,
    float* __restrict__ ws,
    const float* __restrict__ b00, const float* __restrict__ b01, const float* __restrict__ b02,
    const float* __restrict__ b10, const float* __restrict__ b11, const float* __restrict__ b12,
    const float* __restrict__ b20, const float* __restrict__ b21, const float* __restrict__ b22) {
  const int tid = blockIdx.x * 256 + threadIdx.x;
  if (tid >= 315 * 512) return;
  const int blk = tid >> 9;
  const int e   = tid & 511;
  const int tap = blk / 35;
  const int r   = blk - tap * 35;
  const int kc  = r / 5, cj = r - (r / 5) * 5;
  const int l   = e >> 3, j = e & 7;
  const int co  = cj * 16 + (l & 15);
  const int kk  = kc * 32 + ((l >> 4) << 3) + j;
  short val = 0;
  if (co < NCH && kk < 216) {
    const int dx = kk / 72, ci = kk - dx * 72;
    int fi, u, dd, di; chmap(co, fi, u, dd, di);
    int fj, v, ee, dj; chmap(ci, fj, v, ee, dj);
    const float* bs[9] = {b00, b01, b02, b10, b11, b12, b20, b21, b22};
    const float* basis = bs[fi * 3 + fj];
    const float sc = ws[WS_SCALE + ci];
    const float* wp = weight + (fi * 3 + fj) * 128 + (u * 8 + v) * 2;
    const float w0 = wp[0] * sc, w1 = wp[1] * sc;
    const int t = tap * 3 + dx;
    const float f = w0 * basis[(dd * dj + ee) * 27 + t]
                  + w1 * basis[((di + dd) * dj + ee) * 27 + t];
    val = __half_as_short(__float2half(f));
  }
  ((short*)(ws + WS_K))[tid] = val;
}

// ---------------- conv: 2-wave blocks, XCD-swizzled, register-double-buffered pipeline ----
// 1800 blocks x 128 threads (2 waves = 2 adjacent y rows). XCD r = blk%8 = batch.
// Per wave: m-tile 2z x 32x at one y; n = 80 co; k = 2016, flattened into 63 groups
// (tap 0..8 x kc 0..6). Explicit 2-deep register double-buffer: issue group t+1's 9
// 16B loads, MFMA group t -> compiler emits s_waitcnt vmcnt(9) (counted, never 0),
// giving ~390 MFMA-cycles of latency cover per group (> L2 hit latency).
__global__ __launch_bounds__(128, 2) void conv_direct(const float* __restrict__ ws,
                                                      float* __restrict__ out) {
  const int lane = threadIdx.x & 63;
  const int wv   = threadIdx.x >> 6;   // 0..1: y sub-row
  const int lx   = lane & 15;
  const int q    = lane >> 4;
  const int i  = blockIdx.x;
  const int b  = i & 7;                // XCD-pinned batch
  const int qq = i >> 3;               // 0..224
  const int yp = qq % 15;
  const int zp = qq / 15;              // 0..14
  const int y  = yp * 2 + wv;          // 0..29
  const int zb = zp * 2;

  const char* xhb = (const char*)ws + WS_XH_BYTES + (size_t)b * (XH_BATCH * 2);
  const char* Kb  = (const char*)(ws + WS_K);
  const float* __restrict__ bias = ws + WS_BIAS;

  const int lb16 = lane * 16;          // B-fragment: contiguous 1KB block + lane*16

  float4v acc[2][2][5];
  #pragma unroll
  for (int sz = 0; sz < 2; ++sz)
    #pragma unroll
    for (int s = 0; s < 2; ++s)
      #pragma unroll
      for (int cj = 0; cj < 5; ++cj)
        acc[sz][s][cj] = (float4v){0.f, 0.f, 0.f, 0.f};

  // group T = tap*7 + kc; tap = dz*3+dy. All buffer indices compile-time (no scratch).
#define LOADG(T, A, Bf) {                                                         \
    const int t_   = (T);                                                         \
    const int tap_ = t_ / 7;                                                      \
    const int kc_  = t_ - tap_ * 7;                                               \
    const int dz_  = tap_ / 3, dy_ = tap_ - 3 * dz_;                              \
    const char* r0_ = xhb + (size_t)(((zb + dz_) * 32) + (y + dy_)) * (XH_ROW*2); \
    const char* r1_ = r0_ + (XH_PLANE * 2);                                       \
    const char* bk_ = Kb + (size_t)tap_ * (35*1024) + (size_t)kc_ * (5*1024) + lb16; \
    const int kk0_ = kc_ * 32 + (q << 3);                                         \
    const int dx_  = (kk0_ >= 144) ? 2 : ((kk0_ >= 72) ? 1 : 0);                  \
    const int ao_  = (lx * 80 + kk0_ + 8 * dx_) * 2;                              \
    Bf[0] = *(const half8*)(bk_);                                                 \
    Bf[1] = *(const half8*)(bk_ + 1024);                                          \
    Bf[2] = *(const half8*)(bk_ + 2048);                                          \
    Bf[3] = *(const half8*)(bk_ + 3072);                                          \
    Bf[4] = *(const half8*)(bk_ + 4096);                                          \
    A[0] = *(const half8*)(r0_ + ao_);                                            \
    A[1] = *(const half8*)(r0_ + ao_ + 2560);                                     \
    A[2] = *(const half8*)(r1_ + ao_);                                            \
    A[3] = *(const half8*)(r1_ + ao_ + 2560);                                     \
  }

#define MF1(A, Bf, CJ)                                                                         \
    acc[0][0][CJ] = __builtin_amdgcn_mfma_f32_16x16x32_f16(A[0], Bf[CJ], acc[0][0][CJ], 0,0,0); \
    acc[0][1][CJ] = __builtin_amdgcn_mfma_f32_16x16x32_f16(A[1], Bf[CJ], acc[0][1][CJ], 0,0,0); \
    acc[1][0][CJ] = __builtin_amdgcn_mfma_f32_16x16x32_f16(A[2], Bf[CJ], acc[1][0][CJ], 0,0,0); \
    acc[1][1][CJ] = __builtin_amdgcn_mfma_f32_16x16x32_f16(A[3], Bf[CJ], acc[1][1][CJ], 0,0,0);

#define MFMAG(A, Bf) {                       \
    __builtin_amdgcn_s_setprio(1);           \
    MF1(A, Bf, 0) MF1(A, Bf, 1)              \
    MF1(A, Bf, 2) MF1(A, Bf, 3)              \
    MF1(A, Bf, 4)                            \
    __builtin_amdgcn_s_setprio(0);           \
  }

  half8 A0[4], B0[5], A1[4], B1[5];
  LOADG(0, A0, B0);
  #pragma unroll 1
  for (int t = 0; t < 62; t += 2) {
    LOADG(t + 1, A1, B1);   // issue next group's loads (stay in flight: vmcnt(9))
    MFMAG(A0, B0);          // compute current (waits only on its own, older loads)
    LOADG(t + 2, A0, B0);
    MFMAG(A1, B1);
  }
  MFMAG(A0, B0);            // group 62 (loaded in last loop iteration)

#undef LOADG
#undef MF1
#undef MFMAG

  // epilogue: D layout col(co)=lane&15, row(m=x)=q*4+reg
  #pragma unroll
  for (int cj = 0; cj < 5; ++cj) {
    const int co = cj * 16 + lx;
    if (co < NCH) {
      const float bv = bias[co];
      #pragma unroll
      for (int sz = 0; sz < 2; ++sz) {
        float* ob = out + ((size_t)(b * NCH + co) * 30 + (zb + sz)) * 900 + y * 30;
        #pragma unroll
        for (int s = 0; s < 2; ++s) {
          const int x0 = s * 16 + q * 4;
          const float4v v = acc[sz][s][cj];
          float2 p0; p0.x = v[0] + bv; p0.y = v[1] + bv;
          *(float2*)(ob + x0) = p0;
          if (x0 + 2 < 30) {
            float2 p1; p1.x = v[2] + bv; p1.y = v[3] + bv;
            *(float2*)(ob + x0 + 2) = p1;
          }
        }
      }
    }
  }
}

extern "C" void kernel_launch(void* const* d_in, const int* in_sizes, int n_in,
                              void* d_out, int out_size, void* d_ws, size_t ws_size,
                              hipStream_t stream) {
  const float* x = (const float*)d_in[0];
  const float* w = (const float*)d_in[1];
  const float* bs[9];
  for (int i = 0; i < 9; ++i) bs[i] = (const float*)d_in[2 + i];
  float* ws  = (float*)d_ws;
  float* out = (float*)d_out;

  hipMemsetAsync(d_ws, 0, 144 * sizeof(float), stream);   // stats accumulators

  prepack_kernel<<<dim3(64, NBATCH), 256, 0, stream>>>(x, ws);
  finalize_kernel<<<1, 128, 0, stream>>>(w, bs[0], ws);
  build_half_kernel<<<(315 * 512 + 255) / 256, 256, 0, stream>>>(
      w, ws, bs[0], bs[1], bs[2], bs[3], bs[4], bs[5], bs[6], bs[7], bs[8]);
  conv_direct<<<dim3(1800), 128, 0, stream>>>(ws, out);
}

// Round 2
// 281.041 us; speedup vs baseline: 1.2225x; 1.0170x over previous
//
#include <hip/hip_runtime.h>
#include <hip/hip_fp16.h>
#include <math.h>

// Problem constants
#define NCH 72            // total channels (8*1 + 8*3 + 8*5)
#define SP  32768         // 32^3 spatial
#define NBATCH 8
#define NTOT (NBATCH*SP)  // per-channel element count = 262144

// ws layout (float offsets for the small stuff)
#define WS_SUMX   0       // 72
#define WS_SUMSQ  72      // 72
#define WS_SCALE  144     // 72 (unused now; kept for layout stability)
#define WS_BIAS   216     // 72
#define WS_K      288     // fp16 kernel matrix, fragment-blocked: 315 blocks * 1024 B

// byte offsets / strides for the packed fp16 x tensor
#define WS_XH_BYTES 323712          // 288*4 + 322560, 16B aligned
#define XH_ROW   2720               // 34 x-slots * 80 ci  (elements)
#define XH_PLANE 87040              // 32 * XH_ROW
#define XH_BATCH 2785280            // 32 * XH_PLANE

typedef __attribute__((ext_vector_type(8))) _Float16 half8;
typedef __attribute__((ext_vector_type(4))) float float4v;
typedef __attribute__((ext_vector_type(4))) int int4v;

__device__ __forceinline__ void chmap(int c, int& f, int& m, int& d, int& dim) {
  if (c < 8)       { f = 0; m = c;          d = 0;          dim = 1; }
  else if (c < 32) { f = 1; m = (c - 8)/3;  d = (c - 8)%3;  dim = 3; }
  else             { f = 2; m = (c - 32)/5; d = (c - 32)%5; dim = 5; }
}

// ---------------- prepack: x -> fp16 [b][z][y][x(34)][ci(80)] + fused BN stats ----------
// grid (64, 8): blockIdx.x = z*2 + half; block = half a z-plane (2 chunks of 256 pos)
__global__ __launch_bounds__(256) void prepack_kernel(const float* __restrict__ x,
                                                      float* __restrict__ ws) {
  __shared__ __align__(16) short tile[256 * 88];   // [pos(256)][ci(88 pad)] = 45 KB
  __shared__ float segS[72][3], segQ[72][3];
  const int t    = threadIdx.x;
  const int z    = blockIdx.x >> 1;
  const int half = blockIdx.x & 1;
  const int b    = blockIdx.y;
  ushort* xh = (ushort*)((char*)ws + WS_XH_BYTES);
  const float* xb = x + (size_t)b * NCH * SP + z * 1024 + half * 512;

  const int ci_s = t % 72, seg = t / 72;   // stats mapping (t < 216)
  float accS = 0.f, accQ = 0.f;

  // zero the ci pad (72..79) once: phase 2a copies it into the packed tensor, and
  // the conv multiplies it by B=0 -- stale LDS Inf/NaN would make 0*Inf = NaN.
  *(int4v*)&tile[t * 88 + 72] = (int4v){0, 0, 0, 0};

  for (int c = 0; c < 2; ++c) {
    if (c) __syncthreads();                 // protect tile reuse
    // phase 1: coalesced fp32 loads (fully unrolled -> deep MLP), short4 LDS writes
    #pragma unroll
    for (int cig = 0; cig < 18; ++cig) {
      float v0 = xb[(size_t)(cig*4 + 0) * SP + c * 256 + t];
      float v1 = xb[(size_t)(cig*4 + 1) * SP + c * 256 + t];
      float v2 = xb[(size_t)(cig*4 + 2) * SP + c * 256 + t];
      float v3 = xb[(size_t)(cig*4 + 3) * SP + c * 256 + t];
      short s4[4] = { (short)__half_as_short(__float2half(v0)),
                      (short)__half_as_short(__float2half(v1)),
                      (short)__half_as_short(__float2half(v2)),
                      (short)__half_as_short(__float2half(v3)) };
      *(int2*)&tile[t * 88 + cig * 4] = *(const int2*)s4;   // 8B aligned
    }
    __syncthreads();
    // phase 2a: coalesced writeout — 2560 16B segments (10 per pos), consecutive lanes
    {
      ushort* gb = xh + (size_t)b * XH_BATCH + (size_t)(z * 32 + (half * 2 + c) * 8) * XH_ROW;
      #pragma unroll
      for (int j = 0; j < 10; ++j) {
        const int s   = t + j * 256;        // 0..2559
        const int pos = s / 10, part = s - pos * 10;
        const int4v v = *(const int4v*)&tile[pos * 88 + part * 8];
        const int row = pos >> 5, xx = pos & 31;
        *(int4v*)(gb + (size_t)row * XH_ROW + xx * 80 + part * 8) = v;
      }
    }
    // phase 2b: stats from the tile (per-ci column sums)
    if (seg < 3) {
      const int p0 = seg * 86;
      const int pn = (seg == 2) ? 84 : 86;
      for (int i = 0; i < pn; ++i) {
        const float v = __half2float(__short_as_half(tile[(p0 + i) * 88 + ci_s]));
        accS += v; accQ += v * v;
      }
    }
  }
  if (seg < 3) { segS[ci_s][seg] = accS; segQ[ci_s][seg] = accQ; }
  __syncthreads();
  if (t < 144) {
    const int which = t / 72, ci = t % 72;
    const float v = which ? (segQ[ci][0] + segQ[ci][1] + segQ[ci][2])
                          : (segS[ci][0] + segS[ci][1] + segS[ci][2]);
    atomicAdd(&ws[(which ? WS_SUMSQ : WS_SUMX) + ci], v);
  }
}

// ---------------- build fp16 kernel matrix + (block 0) bias; scales computed inline ----
// 315 blocks of 1024 B: block = tap*35 + kc*5 + cj; element e: lane l = e/8, j = e%8;
// co = cj*16 + (l&15);  kk = kc*32 + (l>>4)*8 + j  (zero for co>=72 or kk>=216)
// Inline inverse-std from raw sums removes the separate finalize dispatch.
__global__ __launch_bounds__(256) void build_half_kernel(const float* __restrict__ weight,
    float* __restrict__ ws,
    const float* __restrict__ b00, const float* __restrict__ b01, const float* __restrict__ b02,
    const float* __restrict__ b10, const float* __restrict__ b11, const float* __restrict__ b12,
    const float* __restrict__ b20, const float* __restrict__ b21, const float* __restrict__ b22) {
  const int tid = blockIdx.x * 256 + threadIdx.x;
  const float invN = 1.0f / (float)NTOT;
  if (tid < 315 * 512) {
    const int blk = tid >> 9;
    const int e   = tid & 511;
    const int tap = blk / 35;
    const int r   = blk - tap * 35;
    const int kc  = r / 5, cj = r - (r / 5) * 5;
    const int l   = e >> 3, j = e & 7;
    const int co  = cj * 16 + (l & 15);
    const int kk  = kc * 32 + ((l >> 4) << 3) + j;
    short val = 0;
    if (co < NCH && kk < 216) {
      const int dx = kk / 72, ci = kk - dx * 72;
      int fi, u, dd, di; chmap(co, fi, u, dd, di);
      int fj, v, ee, dj; chmap(ci, fj, v, ee, dj);
      const float* bs[9] = {b00, b01, b02, b10, b11, b12, b20, b21, b22};
      const float* basis = bs[fi * 3 + fj];
      // inverse-std for input channel ci, computed from raw sums
      float norm;
      if (ci < 8) {
        float m = ws[WS_SUMX + ci] * invN;
        norm = ws[WS_SUMSQ + ci] * invN - m * m;
      } else if (ci < 32) {
        int m0 = 8 + ((ci - 8) / 3) * 3;
        norm = (ws[WS_SUMSQ+m0] + ws[WS_SUMSQ+m0+1] + ws[WS_SUMSQ+m0+2]) * invN;
      } else {
        int m0 = 32 + ((ci - 32) / 5) * 5;
        norm = (ws[WS_SUMSQ+m0] + ws[WS_SUMSQ+m0+1] + ws[WS_SUMSQ+m0+2]
              + ws[WS_SUMSQ+m0+3] + ws[WS_SUMSQ+m0+4]) * invN;
      }
      const float sc = 1.0f / sqrtf(norm + 1e-5f);
      const float* wp = weight + (fi * 3 + fj) * 128 + (u * 8 + v) * 2;
      const float w0 = wp[0] * sc, w1 = wp[1] * sc;
      const int t = tap * 3 + dx;
      const float f = w0 * basis[(dd * dj + ee) * 27 + t]
                    + w1 * basis[((di + dd) * dj + ee) * 27 + t];
      val = __half_as_short(__float2half(f));
    }
    ((short*)(ws + WS_K))[tid] = val;
  }
  // block 0: compute compensating bias (72 floats; nonzero only for scalar outputs)
  if (blockIdx.x == 0) {
    __shared__ float s_mean[8], s_scale[8];
    const int c = threadIdx.x;
    if (c < 8) {
      float m = ws[WS_SUMX + c] * invN;
      float norm = ws[WS_SUMSQ + c] * invN - m * m;
      s_mean[c]  = m;
      s_scale[c] = 1.0f / sqrtf(norm + 1e-5f);
    }
    __syncthreads();
    if (c < NCH) {
      float bia = 0.f;
      if (c < 8) {
        float id0 = 0.f, id1 = 0.f;
        #pragma unroll
        for (int t = 0; t < 27; ++t) { id0 += b00[t]; id1 += b00[27 + t]; }
        #pragma unroll
        for (int v = 0; v < 8; ++v) {
          float s  = s_scale[v];
          float w0 = weight[(c*8 + v)*2 + 0] * s;
          float w1 = weight[(c*8 + v)*2 + 1] * s;
          bia -= (w0 * id0 + w1 * id1) * s_mean[v];
        }
      }
      ws[WS_BIAS + c] = bia;
    }
  }
}

// ---------------- conv: 2-wave blocks, XCD-swizzled, 3-deep register pipeline ----------
// 1800 blocks x 128 threads (2 waves = 2 adjacent y rows). XCD r = blk%8 = batch.
// Per wave: m-tile 2z x 32x at one y; n = 80 co; k = 2016, flattened into 63 groups
// (tap 0..8 x kc 0..6). 3-deep rotating register buffer: two groups' loads always in
// flight ahead of the MFMA cluster -> s_waitcnt vmcnt(18) steady state, ~2 groups
// (~300 MFMA-cycles) of latency cover, exceeding L2 hit latency (~200-300 cy).
__global__ __launch_bounds__(128, 2) void conv_direct(const float* __restrict__ ws,
                                                      float* __restrict__ out) {
  const int lane = threadIdx.x & 63;
  const int wv   = threadIdx.x >> 6;   // 0..1: y sub-row
  const int lx   = lane & 15;
  const int q    = lane >> 4;
  const int i  = blockIdx.x;
  const int b  = i & 7;                // XCD-pinned batch
  const int qq = i >> 3;               // 0..224
  const int yp = qq % 15;
  const int zp = qq / 15;              // 0..14
  const int y  = yp * 2 + wv;          // 0..29
  const int zb = zp * 2;

  const char* xhb = (const char*)ws + WS_XH_BYTES + (size_t)b * (XH_BATCH * 2);
  const char* Kb  = (const char*)(ws + WS_K);
  const float* __restrict__ bias = ws + WS_BIAS;

  const int lb16 = lane * 16;          // B-fragment: contiguous 1KB block + lane*16

  float4v acc[2][2][5];
  #pragma unroll
  for (int sz = 0; sz < 2; ++sz)
    #pragma unroll
    for (int s = 0; s < 2; ++s)
      #pragma unroll
      for (int cj = 0; cj < 5; ++cj)
        acc[sz][s][cj] = (float4v){0.f, 0.f, 0.f, 0.f};

  // group T = tap*7 + kc; tap = dz*3+dy. All buffer indices compile-time (no scratch).
#define LOADG(T, A, Bf) {                                                         \
    const int t_   = (T);                                                         \
    const int tap_ = t_ / 7;                                                      \
    const int kc_  = t_ - tap_ * 7;                                               \
    const int dz_  = tap_ / 3, dy_ = tap_ - 3 * dz_;                              \
    const char* r0_ = xhb + (size_t)(((zb + dz_) * 32) + (y + dy_)) * (XH_ROW*2); \
    const char* r1_ = r0_ + (XH_PLANE * 2);                                       \
    const char* bk_ = Kb + (size_t)tap_ * (35*1024) + (size_t)kc_ * (5*1024) + lb16; \
    const int kk0_ = kc_ * 32 + (q << 3);                                         \
    const int dx_  = (kk0_ >= 144) ? 2 : ((kk0_ >= 72) ? 1 : 0);                  \
    const int ao_  = (lx * 80 + kk0_ + 8 * dx_) * 2;                              \
    Bf[0] = *(const half8*)(bk_);                                                 \
    Bf[1] = *(const half8*)(bk_ + 1024);                                          \
    Bf[2] = *(const half8*)(bk_ + 2048);                                          \
    Bf[3] = *(const half8*)(bk_ + 3072);                                          \
    Bf[4] = *(const half8*)(bk_ + 4096);                                          \
    A[0] = *(const half8*)(r0_ + ao_);                                            \
    A[1] = *(const half8*)(r0_ + ao_ + 2560);                                     \
    A[2] = *(const half8*)(r1_ + ao_);                                            \
    A[3] = *(const half8*)(r1_ + ao_ + 2560);                                     \
  }

#define MF1(A, Bf, CJ)                                                                         \
    acc[0][0][CJ] = __builtin_amdgcn_mfma_f32_16x16x32_f16(A[0], Bf[CJ], acc[0][0][CJ], 0,0,0); \
    acc[0][1][CJ] = __builtin_amdgcn_mfma_f32_16x16x32_f16(A[1], Bf[CJ], acc[0][1][CJ], 0,0,0); \
    acc[1][0][CJ] = __builtin_amdgcn_mfma_f32_16x16x32_f16(A[2], Bf[CJ], acc[1][0][CJ], 0,0,0); \
    acc[1][1][CJ] = __builtin_amdgcn_mfma_f32_16x16x32_f16(A[3], Bf[CJ], acc[1][1][CJ], 0,0,0);

#define MFMAG(A, Bf) {                       \
    __builtin_amdgcn_s_setprio(1);           \
    MF1(A, Bf, 0) MF1(A, Bf, 1)              \
    MF1(A, Bf, 2) MF1(A, Bf, 3)              \
    MF1(A, Bf, 4)                            \
    __builtin_amdgcn_s_setprio(0);           \
  }

  half8 A0[4], B0[5], A1[4], B1[5], A2[4], B2[5];
  LOADG(0, A0, B0);
  LOADG(1, A1, B1);
  #pragma unroll 1
  for (int t = 0; t < 60; t += 3) {
    LOADG(t + 2, A2, B2);   // two groups always in flight ahead of the consumer
    MFMAG(A0, B0);
    LOADG(t + 3, A0, B0);
    MFMAG(A1, B1);
    LOADG(t + 4, A1, B1);
    MFMAG(A2, B2);
  }
  LOADG(62, A2, B2);        // groups 60,61 already loaded
  MFMAG(A0, B0);
  MFMAG(A1, B1);
  MFMAG(A2, B2);

#undef LOADG
#undef MF1
#undef MFMAG

  // epilogue: D layout col(co)=lane&15, row(m=x)=q*4+reg
  #pragma unroll
  for (int cj = 0; cj < 5; ++cj) {
    const int co = cj * 16 + lx;
    if (co < NCH) {
      const float bv = bias[co];
      #pragma unroll
      for (int sz = 0; sz < 2; ++sz) {
        float* ob = out + ((size_t)(b * NCH + co) * 30 + (zb + sz)) * 900 + y * 30;
        #pragma unroll
        for (int s = 0; s < 2; ++s) {
          const int x0 = s * 16 + q * 4;
          const float4v v = acc[sz][s][cj];
          float2 p0; p0.x = v[0] + bv; p0.y = v[1] + bv;
          *(float2*)(ob + x0) = p0;
          if (x0 + 2 < 30) {
            float2 p1; p1.x = v[2] + bv; p1.y = v[3] + bv;
            *(float2*)(ob + x0 + 2) = p1;
          }
        }
      }
    }
  }
}

extern "C" void kernel_launch(void* const* d_in, const int* in_sizes, int n_in,
                              void* d_out, int out_size, void* d_ws, size_t ws_size,
                              hipStream_t stream) {
  const float* x = (const float*)d_in[0];
  const float* w = (const float*)d_in[1];
  const float* bs[9];
  for (int i = 0; i < 9; ++i) bs[i] = (const float*)d_in[2 + i];
  float* ws  = (float*)d_ws;
  float* out = (float*)d_out;

  hipMemsetAsync(d_ws, 0, 144 * sizeof(float), stream);   // stats accumulators

  prepack_kernel<<<dim3(64, NBATCH), 256, 0, stream>>>(x, ws);
  build_half_kernel<<<(315 * 512 + 255) / 256, 256, 0, stream>>>(
      w, ws, bs[0], bs[1], bs[2], bs[3], bs[4], bs[5], bs[6], bs[7], bs[8]);
  conv_direct<<<dim3(1800), 128, 0, stream>>>(ws, out);
}

// Round 3
// 255.924 us; speedup vs baseline: 1.3425x; 1.0981x over previous
//
#include <hip/hip_runtime.h>
#include <hip/hip_fp16.h>
#include <math.h>

// Problem constants
#define NCH 72            // total channels (8*1 + 8*3 + 8*5)
#define SP  32768         // 32^3 spatial
#define NBATCH 8
#define NTOT (NBATCH*SP)  // per-channel element count = 262144

// ws layout (float offsets for the small stuff)
#define WS_SUMX   0       // 72
#define WS_SUMSQ  72      // 72
#define WS_SCALE  144     // 72 (unused now; kept for layout stability)
#define WS_BIAS   216     // 72
#define WS_K      288     // fp16 kernel matrix, fragment-blocked: 315 blocks * 1024 B

// byte offsets / strides for the packed fp16 x tensor
#define WS_XH_BYTES 323712          // 288*4 + 322560, 16B aligned
#define XH_ROW   2720               // 34 x-slots * 80 ci  (elements)
#define XH_PLANE 87040              // 32 * XH_ROW
#define XH_BATCH 2785280            // 32 * XH_PLANE

typedef __attribute__((ext_vector_type(8))) _Float16 half8;
typedef __attribute__((ext_vector_type(4))) float float4v;
typedef __attribute__((ext_vector_type(4))) int int4v;

__device__ __forceinline__ void chmap(int c, int& f, int& m, int& d, int& dim) {
  if (c < 8)       { f = 0; m = c;          d = 0;          dim = 1; }
  else if (c < 32) { f = 1; m = (c - 8)/3;  d = (c - 8)%3;  dim = 3; }
  else             { f = 2; m = (c - 32)/5; d = (c - 32)%5; dim = 5; }
}

// ---------------- prepack: x -> fp16 [b][z][y][x(34)][ci(80)] + fused BN stats ----------
// grid (64, 8): blockIdx.x = z*2 + half; block = half a z-plane (2 chunks of 256 pos)
__global__ __launch_bounds__(256) void prepack_kernel(const float* __restrict__ x,
                                                      float* __restrict__ ws) {
  __shared__ __align__(16) short tile[256 * 88];   // [pos(256)][ci(88 pad)] = 45 KB
  __shared__ float segS[72][3], segQ[72][3];
  const int t    = threadIdx.x;
  const int z    = blockIdx.x >> 1;
  const int half = blockIdx.x & 1;
  const int b    = blockIdx.y;
  ushort* xh = (ushort*)((char*)ws + WS_XH_BYTES);
  const float* xb = x + (size_t)b * NCH * SP + z * 1024 + half * 512;

  const int ci_s = t % 72, seg = t / 72;   // stats mapping (t < 216)
  float accS = 0.f, accQ = 0.f;

  // zero the ci pad (72..79) once: phase 2a copies it into the packed tensor, and
  // the conv multiplies it by B=0 -- stale LDS Inf/NaN would make 0*Inf = NaN.
  *(int4v*)&tile[t * 88 + 72] = (int4v){0, 0, 0, 0};

  for (int c = 0; c < 2; ++c) {
    if (c) __syncthreads();                 // protect tile reuse
    // phase 1: coalesced fp32 loads (fully unrolled -> deep MLP), short4 LDS writes
    #pragma unroll
    for (int cig = 0; cig < 18; ++cig) {
      float v0 = xb[(size_t)(cig*4 + 0) * SP + c * 256 + t];
      float v1 = xb[(size_t)(cig*4 + 1) * SP + c * 256 + t];
      float v2 = xb[(size_t)(cig*4 + 2) * SP + c * 256 + t];
      float v3 = xb[(size_t)(cig*4 + 3) * SP + c * 256 + t];
      short s4[4] = { (short)__half_as_short(__float2half(v0)),
                      (short)__half_as_short(__float2half(v1)),
                      (short)__half_as_short(__float2half(v2)),
                      (short)__half_as_short(__float2half(v3)) };
      *(int2*)&tile[t * 88 + cig * 4] = *(const int2*)s4;   // 8B aligned
    }
    __syncthreads();
    // phase 2a: coalesced writeout — 2560 16B segments (10 per pos), consecutive lanes
    {
      ushort* gb = xh + (size_t)b * XH_BATCH + (size_t)(z * 32 + (half * 2 + c) * 8) * XH_ROW;
      #pragma unroll
      for (int j = 0; j < 10; ++j) {
        const int s   = t + j * 256;        // 0..2559
        const int pos = s / 10, part = s - pos * 10;
        const int4v v = *(const int4v*)&tile[pos * 88 + part * 8];
        const int row = pos >> 5, xx = pos & 31;
        *(int4v*)(gb + (size_t)row * XH_ROW + xx * 80 + part * 8) = v;
      }
    }
    // phase 2b: stats from the tile (per-ci column sums)
    if (seg < 3) {
      const int p0 = seg * 86;
      const int pn = (seg == 2) ? 84 : 86;
      for (int i = 0; i < pn; ++i) {
        const float v = __half2float(__short_as_half(tile[(p0 + i) * 88 + ci_s]));
        accS += v; accQ += v * v;
      }
    }
  }
  if (seg < 3) { segS[ci_s][seg] = accS; segQ[ci_s][seg] = accQ; }
  __syncthreads();
  if (t < 144) {
    const int which = t / 72, ci = t % 72;
    const float v = which ? (segQ[ci][0] + segQ[ci][1] + segQ[ci][2])
                          : (segS[ci][0] + segS[ci][1] + segS[ci][2]);
    atomicAdd(&ws[(which ? WS_SUMSQ : WS_SUMX) + ci], v);
  }
}

// ---------------- build fp16 kernel matrix + (block 0) bias; scales computed inline ----
// 315 blocks of 1024 B: block = tap*35 + kc*5 + cj; element e: lane l = e/8, j = e%8;
// co = cj*16 + (l&15);  kk = kc*32 + (l>>4)*8 + j  (zero for co>=72 or kk>=216)
__global__ __launch_bounds__(256) void build_half_kernel(const float* __restrict__ weight,
    float* __restrict__ ws,
    const float* __restrict__ b00, const float* __restrict__ b01, const float* __restrict__ b02,
    const float* __restrict__ b10, const float* __restrict__ b11, const float* __restrict__ b12,
    const float* __restrict__ b20, const float* __restrict__ b21, const float* __restrict__ b22) {
  const int tid = blockIdx.x * 256 + threadIdx.x;
  const float invN = 1.0f / (float)NTOT;
  if (tid < 315 * 512) {
    const int blk = tid >> 9;
    const int e   = tid & 511;
    const int tap = blk / 35;
    const int r   = blk - tap * 35;
    const int kc  = r / 5, cj = r - (r / 5) * 5;
    const int l   = e >> 3, j = e & 7;
    const int co  = cj * 16 + (l & 15);
    const int kk  = kc * 32 + ((l >> 4) << 3) + j;
    short val = 0;
    if (co < NCH && kk < 216) {
      const int dx = kk / 72, ci = kk - dx * 72;
      int fi, u, dd, di; chmap(co, fi, u, dd, di);
      int fj, v, ee, dj; chmap(ci, fj, v, ee, dj);
      const float* bs[9] = {b00, b01, b02, b10, b11, b12, b20, b21, b22};
      const float* basis = bs[fi * 3 + fj];
      // inverse-std for input channel ci, computed from raw sums
      float norm;
      if (ci < 8) {
        float m = ws[WS_SUMX + ci] * invN;
        norm = ws[WS_SUMSQ + ci] * invN - m * m;
      } else if (ci < 32) {
        int m0 = 8 + ((ci - 8) / 3) * 3;
        norm = (ws[WS_SUMSQ+m0] + ws[WS_SUMSQ+m0+1] + ws[WS_SUMSQ+m0+2]) * invN;
      } else {
        int m0 = 32 + ((ci - 32) / 5) * 5;
        norm = (ws[WS_SUMSQ+m0] + ws[WS_SUMSQ+m0+1] + ws[WS_SUMSQ+m0+2]
              + ws[WS_SUMSQ+m0+3] + ws[WS_SUMSQ+m0+4]) * invN;
      }
      const float sc = 1.0f / sqrtf(norm + 1e-5f);
      const float* wp = weight + (fi * 3 + fj) * 128 + (u * 8 + v) * 2;
      const float w0 = wp[0] * sc, w1 = wp[1] * sc;
      const int t = tap * 3 + dx;
      const float f = w0 * basis[(dd * dj + ee) * 27 + t]
                    + w1 * basis[((di + dd) * dj + ee) * 27 + t];
      val = __half_as_short(__float2half(f));
    }
    ((short*)(ws + WS_K))[tid] = val;
  }
  // block 0: compute compensating bias (72 floats; nonzero only for scalar outputs)
  if (blockIdx.x == 0) {
    __shared__ float s_mean[8], s_scale[8];
    const int c = threadIdx.x;
    if (c < 8) {
      float m = ws[WS_SUMX + c] * invN;
      float norm = ws[WS_SUMSQ + c] * invN - m * m;
      s_mean[c]  = m;
      s_scale[c] = 1.0f / sqrtf(norm + 1e-5f);
    }
    __syncthreads();
    if (c < NCH) {
      float bia = 0.f;
      if (c < 8) {
        float id0 = 0.f, id1 = 0.f;
        #pragma unroll
        for (int t = 0; t < 27; ++t) { id0 += b00[t]; id1 += b00[27 + t]; }
        #pragma unroll
        for (int v = 0; v < 8; ++v) {
          float s  = s_scale[v];
          float w0 = weight[(c*8 + v)*2 + 0] * s;
          float w1 = weight[(c*8 + v)*2 + 1] * s;
          bia -= (w0 * id0 + w1 * id1) * s_mean[v];
        }
      }
      ws[WS_BIAS + c] = bia;
    }
  }
}

// ---------------- conv: 4-wave blocks, B staged in LDS via global_load_lds ----------
// 960 blocks x 256 threads (4 waves = 4 adjacent y rows; y-tile 8 covers y 28..31 with
// clamped loads / masked stores). XCD r = blk%8 = batch. Per wave: m-tile 2z x 32x at
// one y; n = 80 co; k = 2016 as 9 taps x 7 kc-groups.
// Per tap: stage 35 KB B-slice to LDS once per block (9 global_load_lds x16B per
// thread), counted s_waitcnt vmcnt(8) so the 8 A-prefetch loads stay in flight across
// the barrier; B fragments then come from the LDS pipe (ds_read_b128), cutting the
// vector-memory/L2 read traffic by ~45% and sharing B across 4 waves.
__global__ __launch_bounds__(256, 2) void conv_direct(const float* __restrict__ ws,
                                                      float* __restrict__ out) {
  __shared__ __align__(16) char Bsm[35840];   // one tap's B: 35 frag-blocks * 1024 B

  const int lane = threadIdx.x & 63;
  const int wv   = threadIdx.x >> 6;   // 0..3: y sub-row
  const int lx   = lane & 15;
  const int q    = lane >> 4;
  const int i  = blockIdx.x;
  const int b  = i & 7;                // XCD-pinned batch
  const int q2 = i >> 3;               // 0..119
  const int yt = q2 & 7;               // 8 y-tiles of 4
  const int zp = q2 >> 3;              // 0..14
  const int y  = yt * 4 + wv;          // 0..31 (30,31 are clamp-duplicates)
  const int yc = (y > 29) ? 29 : y;    // clamped row for loads (keeps reads in-bounds)
  const int zb = zp * 2;

  const char* xhb = (const char*)ws + WS_XH_BYTES + (size_t)b * (XH_BATCH * 2);
  const char* Kb  = (const char*)(ws + WS_K);
  const float* __restrict__ bias = ws + WS_BIAS;

  const int lb16 = lane * 16;          // B-fragment: contiguous 1KB block + lane*16

  float4v acc[2][2][5];
  #pragma unroll
  for (int sz = 0; sz < 2; ++sz)
    #pragma unroll
    for (int s = 0; s < 2; ++s)
      #pragma unroll
      for (int cj = 0; cj < 5; ++cj)
        acc[sz][s][cj] = (float4v){0.f, 0.f, 0.f, 0.f};

  // stage one tap's 35840 B: 2240 x 16B chunks; thread t handles t + k*256.
  // LDS dest is wave-uniform base + lane*16 (HW rule); all masks wave-uniform.
#define STAGE(TAP) {                                                              \
    const char* src_ = Kb + (size_t)(TAP) * 35840;                                \
    _Pragma("unroll")                                                             \
    for (int k = 0; k < 9; ++k) {                                                 \
      const int idx = (int)threadIdx.x + (k << 8);                                \
      if (idx < 2240) {                                                           \
        __builtin_amdgcn_global_load_lds(                                         \
          (const __attribute__((address_space(1))) void*)(src_ + (size_t)idx*16), \
          (__attribute__((address_space(3))) void*)(Bsm + ((k<<8) + (wv<<6))*16), \
          16, 0, 0);                                                              \
      }                                                                           \
    }                                                                             \
  }

#define LOADA(KC, A) {                                                            \
    const int kk0_ = (KC) * 32 + (q << 3);                                        \
    const int dx_  = (kk0_ >= 144) ? 2 : ((kk0_ >= 72) ? 1 : 0);                  \
    const int ao_  = (lx * 80 + kk0_ + 8 * dx_) * 2;                              \
    A[0] = *(const half8*)(r0T + ao_);                                            \
    A[1] = *(const half8*)(r0T + ao_ + 2560);                                     \
    A[2] = *(const half8*)(r1T + ao_);                                            \
    A[3] = *(const half8*)(r1T + ao_ + 2560);                                     \
  }

#define MFQ(A, BF, CJ)                                                                         \
    acc[0][0][CJ] = __builtin_amdgcn_mfma_f32_16x16x32_f16(A[0], BF, acc[0][0][CJ], 0,0,0);    \
    acc[0][1][CJ] = __builtin_amdgcn_mfma_f32_16x16x32_f16(A[1], BF, acc[0][1][CJ], 0,0,0);    \
    acc[1][0][CJ] = __builtin_amdgcn_mfma_f32_16x16x32_f16(A[2], BF, acc[1][0][CJ], 0,0,0);    \
    acc[1][1][CJ] = __builtin_amdgcn_mfma_f32_16x16x32_f16(A[3], BF, acc[1][1][CJ], 0,0,0);

#define GROUP(KC, AC, PRE) {                                                      \
    half8 bf0 = *(const half8*)(Bsm + ((KC)*5 + 0)*1024 + lb16);                  \
    half8 bf1 = *(const half8*)(Bsm + ((KC)*5 + 1)*1024 + lb16);                  \
    half8 bf2 = *(const half8*)(Bsm + ((KC)*5 + 2)*1024 + lb16);                  \
    half8 bf3 = *(const half8*)(Bsm + ((KC)*5 + 3)*1024 + lb16);                  \
    half8 bf4 = *(const half8*)(Bsm + ((KC)*5 + 4)*1024 + lb16);                  \
    PRE;                                                                          \
    __builtin_amdgcn_s_setprio(1);                                                \
    MFQ(AC, bf0, 0) MFQ(AC, bf1, 1) MFQ(AC, bf2, 2) MFQ(AC, bf3, 3) MFQ(AC, bf4, 4) \
    __builtin_amdgcn_s_setprio(0);                                                \
  }

  half8 A0[4], A1[4], A2[4];

  #pragma unroll 1
  for (int tap = 0; tap < 9; ++tap) {
    const int dz_ = tap / 3, dy_ = tap - dz_ * 3;
    const char* r0T = xhb + (size_t)(((zb + dz_) * 32) + (yc + dy_)) * (XH_ROW * 2);
    const char* r1T = r0T + (XH_PLANE * 2);

    if (tap) __builtin_amdgcn_s_barrier();   // all waves done reading previous B
    STAGE(tap);                              // 9 global_load_lds (oldest in vmcnt)
    __builtin_amdgcn_sched_barrier(0);
    LOADA(0, A0); LOADA(1, A1);              // A prefetch (8 loads, younger)
    __builtin_amdgcn_sched_barrier(0);
    asm volatile("s_waitcnt vmcnt(8)" ::: "memory");   // staging done; A in flight
    __builtin_amdgcn_s_barrier();            // staged B visible to all waves
    __builtin_amdgcn_sched_barrier(0);

    GROUP(0, A0, LOADA(2, A2));
    GROUP(1, A1, LOADA(3, A0));
    GROUP(2, A2, LOADA(4, A1));
    GROUP(3, A0, LOADA(5, A2));
    GROUP(4, A1, LOADA(6, A0));
    GROUP(5, A2, (void)0);
    GROUP(6, A0, (void)0);
  }

#undef STAGE
#undef LOADA
#undef MFQ
#undef GROUP

  // epilogue: D layout col(co)=lane&15, row(m=x)=q*4+reg; y>=30 waves are clamp-dupes
  if (y < 30) {
    #pragma unroll
    for (int cj = 0; cj < 5; ++cj) {
      const int co = cj * 16 + lx;
      if (co < NCH) {
        const float bv = bias[co];
        #pragma unroll
        for (int sz = 0; sz < 2; ++sz) {
          float* ob = out + ((size_t)(b * NCH + co) * 30 + (zb + sz)) * 900 + y * 30;
          #pragma unroll
          for (int s = 0; s < 2; ++s) {
            const int x0 = s * 16 + q * 4;
            const float4v v = acc[sz][s][cj];
            float2 p0; p0.x = v[0] + bv; p0.y = v[1] + bv;
            *(float2*)(ob + x0) = p0;
            if (x0 + 2 < 30) {
              float2 p1; p1.x = v[2] + bv; p1.y = v[3] + bv;
              *(float2*)(ob + x0 + 2) = p1;
            }
          }
        }
      }
    }
  }
}

extern "C" void kernel_launch(void* const* d_in, const int* in_sizes, int n_in,
                              void* d_out, int out_size, void* d_ws, size_t ws_size,
                              hipStream_t stream) {
  const float* x = (const float*)d_in[0];
  const float* w = (const float*)d_in[1];
  const float* bs[9];
  for (int i = 0; i < 9; ++i) bs[i] = (const float*)d_in[2 + i];
  float* ws  = (float*)d_ws;
  float* out = (float*)d_out;

  hipMemsetAsync(d_ws, 0, 144 * sizeof(float), stream);   // stats accumulators

  prepack_kernel<<<dim3(64, NBATCH), 256, 0, stream>>>(x, ws);
  build_half_kernel<<<(315 * 512 + 255) / 256, 256, 0, stream>>>(
      w, ws, bs[0], bs[1], bs[2], bs[3], bs[4], bs[5], bs[6], bs[7], bs[8]);
  conv_direct<<<dim3(960), 256, 0, stream>>>(ws, out);
}

// Round 4
// 255.897 us; speedup vs baseline: 1.3427x; 1.0001x over previous
//
#include <hip/hip_runtime.h>
#include <hip/hip_fp16.h>
#include <math.h>

// Problem constants
#define NCH 72            // total channels (8*1 + 8*3 + 8*5)
#define SP  32768         // 32^3 spatial
#define NBATCH 8
#define NTOT (NBATCH*SP)  // per-channel element count = 262144

// ws layout (float offsets for the small stuff)
#define WS_SUMX   0       // 72
#define WS_SUMSQ  72      // 72
#define WS_SCALE  144     // 72 (unused now; kept for layout stability)
#define WS_BIAS   216     // 72
#define WS_K      288     // fp16 kernel matrix, fragment-blocked: 315 blocks * 1024 B

// byte offsets / strides for the packed fp16 x tensor
#define WS_XH_BYTES 323712          // 288*4 + 322560, 16B aligned
#define XH_ROW   2720               // 34 x-slots * 80 ci  (elements)
#define XH_PLANE 87040              // 32 * XH_ROW
#define XH_BATCH 2785280            // 32 * XH_PLANE

typedef __attribute__((ext_vector_type(8))) _Float16 half8;
typedef __attribute__((ext_vector_type(4))) float float4v;
typedef __attribute__((ext_vector_type(4))) int int4v;

__device__ __forceinline__ void chmap(int c, int& f, int& m, int& d, int& dim) {
  if (c < 8)       { f = 0; m = c;          d = 0;          dim = 1; }
  else if (c < 32) { f = 1; m = (c - 8)/3;  d = (c - 8)%3;  dim = 3; }
  else             { f = 2; m = (c - 32)/5; d = (c - 32)%5; dim = 5; }
}

// ---------------- prepack: x -> fp16 [b][z][y][x(34)][ci(80)] + fused BN stats ----------
// grid (64, 8): blockIdx.x = z*2 + half; block = half a z-plane (2 chunks of 256 pos)
__global__ __launch_bounds__(256) void prepack_kernel(const float* __restrict__ x,
                                                      float* __restrict__ ws) {
  __shared__ __align__(16) short tile[256 * 88];   // [pos(256)][ci(88 pad)] = 45 KB
  __shared__ float segS[72][3], segQ[72][3];
  const int t    = threadIdx.x;
  const int z    = blockIdx.x >> 1;
  const int half = blockIdx.x & 1;
  const int b    = blockIdx.y;
  ushort* xh = (ushort*)((char*)ws + WS_XH_BYTES);
  const float* xb = x + (size_t)b * NCH * SP + z * 1024 + half * 512;

  const int ci_s = t % 72, seg = t / 72;   // stats mapping (t < 216)
  float accS = 0.f, accQ = 0.f;

  // zero the ci pad (72..79) once: phase 2a copies it into the packed tensor, and
  // the conv multiplies it by B=0 -- stale LDS Inf/NaN would make 0*Inf = NaN.
  *(int4v*)&tile[t * 88 + 72] = (int4v){0, 0, 0, 0};

  for (int c = 0; c < 2; ++c) {
    if (c) __syncthreads();                 // protect tile reuse
    // phase 1: coalesced fp32 loads (fully unrolled -> deep MLP), short4 LDS writes
    #pragma unroll
    for (int cig = 0; cig < 18; ++cig) {
      float v0 = xb[(size_t)(cig*4 + 0) * SP + c * 256 + t];
      float v1 = xb[(size_t)(cig*4 + 1) * SP + c * 256 + t];
      float v2 = xb[(size_t)(cig*4 + 2) * SP + c * 256 + t];
      float v3 = xb[(size_t)(cig*4 + 3) * SP + c * 256 + t];
      short s4[4] = { (short)__half_as_short(__float2half(v0)),
                      (short)__half_as_short(__float2half(v1)),
                      (short)__half_as_short(__float2half(v2)),
                      (short)__half_as_short(__float2half(v3)) };
      *(int2*)&tile[t * 88 + cig * 4] = *(const int2*)s4;   // 8B aligned
    }
    __syncthreads();
    // phase 2a: coalesced writeout — 2560 16B segments (10 per pos), consecutive lanes
    {
      ushort* gb = xh + (size_t)b * XH_BATCH + (size_t)(z * 32 + (half * 2 + c) * 8) * XH_ROW;
      #pragma unroll
      for (int j = 0; j < 10; ++j) {
        const int s   = t + j * 256;        // 0..2559
        const int pos = s / 10, part = s - pos * 10;
        const int4v v = *(const int4v*)&tile[pos * 88 + part * 8];
        const int row = pos >> 5, xx = pos & 31;
        *(int4v*)(gb + (size_t)row * XH_ROW + xx * 80 + part * 8) = v;
      }
    }
    // phase 2b: stats from the tile (per-ci column sums)
    if (seg < 3) {
      const int p0 = seg * 86;
      const int pn = (seg == 2) ? 84 : 86;
      for (int i = 0; i < pn; ++i) {
        const float v = __half2float(__short_as_half(tile[(p0 + i) * 88 + ci_s]));
        accS += v; accQ += v * v;
      }
    }
  }
  if (seg < 3) { segS[ci_s][seg] = accS; segQ[ci_s][seg] = accQ; }
  __syncthreads();
  if (t < 144) {
    const int which = t / 72, ci = t % 72;
    const float v = which ? (segQ[ci][0] + segQ[ci][1] + segQ[ci][2])
                          : (segS[ci][0] + segS[ci][1] + segS[ci][2]);
    atomicAdd(&ws[(which ? WS_SUMSQ : WS_SUMX) + ci], v);
  }
}

// ---------------- build fp16 kernel matrix + (block 0) bias; scales computed inline ----
__global__ __launch_bounds__(256) void build_half_kernel(const float* __restrict__ weight,
    float* __restrict__ ws,
    const float* __restrict__ b00, const float* __restrict__ b01, const float* __restrict__ b02,
    const float* __restrict__ b10, const float* __restrict__ b11, const float* __restrict__ b12,
    const float* __restrict__ b20, const float* __restrict__ b21, const float* __restrict__ b22) {
  const int tid = blockIdx.x * 256 + threadIdx.x;
  const float invN = 1.0f / (float)NTOT;
  if (tid < 315 * 512) {
    const int blk = tid >> 9;
    const int e   = tid & 511;
    const int tap = blk / 35;
    const int r   = blk - tap * 35;
    const int kc  = r / 5, cj = r - (r / 5) * 5;
    const int l   = e >> 3, j = e & 7;
    const int co  = cj * 16 + (l & 15);
    const int kk  = kc * 32 + ((l >> 4) << 3) + j;
    short val = 0;
    if (co < NCH && kk < 216) {
      const int dx = kk / 72, ci = kk - dx * 72;
      int fi, u, dd, di; chmap(co, fi, u, dd, di);
      int fj, v, ee, dj; chmap(ci, fj, v, ee, dj);
      const float* bs[9] = {b00, b01, b02, b10, b11, b12, b20, b21, b22};
      const float* basis = bs[fi * 3 + fj];
      // inverse-std for input channel ci, computed from raw sums
      float norm;
      if (ci < 8) {
        float m = ws[WS_SUMX + ci] * invN;
        norm = ws[WS_SUMSQ + ci] * invN - m * m;
      } else if (ci < 32) {
        int m0 = 8 + ((ci - 8) / 3) * 3;
        norm = (ws[WS_SUMSQ+m0] + ws[WS_SUMSQ+m0+1] + ws[WS_SUMSQ+m0+2]) * invN;
      } else {
        int m0 = 32 + ((ci - 32) / 5) * 5;
        norm = (ws[WS_SUMSQ+m0] + ws[WS_SUMSQ+m0+1] + ws[WS_SUMSQ+m0+2]
              + ws[WS_SUMSQ+m0+3] + ws[WS_SUMSQ+m0+4]) * invN;
      }
      const float sc = 1.0f / sqrtf(norm + 1e-5f);
      const float* wp = weight + (fi * 3 + fj) * 128 + (u * 8 + v) * 2;
      const float w0 = wp[0] * sc, w1 = wp[1] * sc;
      const int t = tap * 3 + dx;
      const float f = w0 * basis[(dd * dj + ee) * 27 + t]
                    + w1 * basis[((di + dd) * dj + ee) * 27 + t];
      val = __half_as_short(__float2half(f));
    }
    ((short*)(ws + WS_K))[tid] = val;
  }
  // block 0: compute compensating bias (72 floats; nonzero only for scalar outputs)
  if (blockIdx.x == 0) {
    __shared__ float s_mean[8], s_scale[8];
    const int c = threadIdx.x;
    if (c < 8) {
      float m = ws[WS_SUMX + c] * invN;
      float norm = ws[WS_SUMSQ + c] * invN - m * m;
      s_mean[c]  = m;
      s_scale[c] = 1.0f / sqrtf(norm + 1e-5f);
    }
    __syncthreads();
    if (c < NCH) {
      float bia = 0.f;
      if (c < 8) {
        float id0 = 0.f, id1 = 0.f;
        #pragma unroll
        for (int t = 0; t < 27; ++t) { id0 += b00[t]; id1 += b00[27 + t]; }
        #pragma unroll
        for (int v = 0; v < 8; ++v) {
          float s  = s_scale[v];
          float w0 = weight[(c*8 + v)*2 + 0] * s;
          float w1 = weight[(c*8 + v)*2 + 1] * s;
          bia -= (w0 * id0 + w1 * id1) * s_mean[v];
        }
      }
      ws[WS_BIAS + c] = bia;
    }
  }
}

// ---------------- conv: 4-wave blocks, double-buffered B in LDS, pipelined taps ------
// 960 blocks x 256 threads (4 y rows/block; y 30,31 clamp-duplicated). XCD r = batch.
// Tap pipeline: stage tap t+1's 35KB B-slice into Bsm[nxt] at the TOP of tap t (9
// global_load_lds), compute tap t from Bsm[cur]; ONE barrier per tap. The staging
// drain rides the compiler's in-order counted vmcnt for the kc=6 A-load. B fragments
// are prefetched one group ahead into registers (counted lgkmcnt, no per-group drain);
// A rotates through 3 buffers with cross-tap prefetch (period 21 = 3 taps).
__global__ __launch_bounds__(256, 2) void conv_direct(const float* __restrict__ ws,
                                                      float* __restrict__ out) {
  extern __shared__ __align__(16) char Bsm[];   // 2 x 35840 B (dynamic: 71680)

  const int lane = threadIdx.x & 63;
  const int wv   = threadIdx.x >> 6;   // 0..3: y sub-row
  const int lx   = lane & 15;
  const int q    = lane >> 4;
  const int i  = blockIdx.x;
  const int b  = i & 7;                // XCD-pinned batch
  const int q2 = i >> 3;               // 0..119
  const int yt = q2 & 7;               // 8 y-tiles of 4
  const int zp = q2 >> 3;              // 0..14
  const int y  = yt * 4 + wv;          // 0..31 (30,31 are clamp-duplicates)
  const int yc = (y > 29) ? 29 : y;    // clamped row for loads (keeps reads in-bounds)
  const int zb = zp * 2;

  const char* xhb = (const char*)ws + WS_XH_BYTES + (size_t)b * (XH_BATCH * 2);
  const char* Kb  = (const char*)(ws + WS_K);
  const float* __restrict__ bias = ws + WS_BIAS;

  const int lb16 = lane * 16;          // B-fragment: contiguous 1KB block + lane*16

  float4v acc[2][2][5];
  #pragma unroll
  for (int sz = 0; sz < 2; ++sz)
    #pragma unroll
    for (int s = 0; s < 2; ++s)
      #pragma unroll
      for (int cj = 0; cj < 5; ++cj)
        acc[sz][s][cj] = (float4v){0.f, 0.f, 0.f, 0.f};

  // stage one tap's 35840 B into buffer BUF: 2240 x 16B chunks, thread t -> t + k*256.
  // LDS dest is wave-uniform base + lane*16 (HW rule); the k=8 tail mask is wave-uniform.
#define STAGE(TAP, BUF) {                                                         \
    const char* src_ = Kb + (size_t)(TAP) * 35840;                                \
    char* dst_ = Bsm + (size_t)(BUF) * 35840;                                     \
    _Pragma("unroll")                                                             \
    for (int k = 0; k < 9; ++k) {                                                 \
      const int idx = (int)threadIdx.x + (k << 8);                                \
      if (idx < 2240) {                                                           \
        __builtin_amdgcn_global_load_lds(                                         \
          (const __attribute__((address_space(1))) void*)(src_ + (size_t)idx*16), \
          (__attribute__((address_space(3))) void*)(dst_ + ((k<<8) + (wv<<6))*16),\
          16, 0, 0);                                                              \
      }                                                                           \
    }                                                                             \
  }

#define LOADA(R0, R1, KC, A) {                                                    \
    const int kk0_ = (KC) * 32 + (q << 3);                                        \
    const int dx_  = (kk0_ >= 144) ? 2 : ((kk0_ >= 72) ? 1 : 0);                  \
    const int ao_  = (lx * 80 + kk0_ + 8 * dx_) * 2;                              \
    A[0] = *(const half8*)((R0) + ao_);                                           \
    A[1] = *(const half8*)((R0) + ao_ + 2560);                                    \
    A[2] = *(const half8*)((R1) + ao_);                                           \
    A[3] = *(const half8*)((R1) + ao_ + 2560);                                    \
  }

#define BPRE(BC, KC, BQ) {                                                        \
    BQ[0] = *(const half8*)((BC) + ((KC)*5 + 0)*1024 + lb16);                     \
    BQ[1] = *(const half8*)((BC) + ((KC)*5 + 1)*1024 + lb16);                     \
    BQ[2] = *(const half8*)((BC) + ((KC)*5 + 2)*1024 + lb16);                     \
    BQ[3] = *(const half8*)((BC) + ((KC)*5 + 3)*1024 + lb16);                     \
    BQ[4] = *(const half8*)((BC) + ((KC)*5 + 4)*1024 + lb16);                     \
  }

#define MFQ(A, BF, CJ)                                                                         \
    acc[0][0][CJ] = __builtin_amdgcn_mfma_f32_16x16x32_f16(A[0], BF, acc[0][0][CJ], 0,0,0);    \
    acc[0][1][CJ] = __builtin_amdgcn_mfma_f32_16x16x32_f16(A[1], BF, acc[0][1][CJ], 0,0,0);    \
    acc[1][0][CJ] = __builtin_amdgcn_mfma_f32_16x16x32_f16(A[2], BF, acc[1][0][CJ], 0,0,0);    \
    acc[1][1][CJ] = __builtin_amdgcn_mfma_f32_16x16x32_f16(A[3], BF, acc[1][1][CJ], 0,0,0);

#define MFMAG(A, BQ) {                                                            \
    __builtin_amdgcn_s_setprio(1);                                                \
    MFQ(A, BQ[0], 0) MFQ(A, BQ[1], 1) MFQ(A, BQ[2], 2) MFQ(A, BQ[3], 3) MFQ(A, BQ[4], 4) \
    __builtin_amdgcn_s_setprio(0);                                                \
  }

  // One tap: entering with X=A(T,0), Y=A(T,1) in flight and Bsm[T&1] staged+visible.
  // Lines: {prefetch B(kc+1)} {prefetch A(kc+2) / next-tap A} {MFMA group kc}.
#define TAPBODY(TT, X, Y, Z) {                                                    \
    const int T_  = (TT);                                                         \
    const int dz_ = T_ / 3, dy_ = T_ - 3 * dz_;                                   \
    const char* r0T = xhb + (size_t)(((zb + dz_) * 32) + (yc + dy_)) * (XH_ROW*2);\
    const char* r1T = r0T + (XH_PLANE * 2);                                       \
    const char* Bc  = Bsm + (size_t)(T_ & 1) * 35840;                             \
    BPRE(Bc, 0, Bq0);                                                             \
    if (T_ < 8) STAGE(T_ + 1, ((T_ + 1) & 1));                                    \
    const int Tn_  = (T_ < 8) ? T_ + 1 : T_;                                      \
    const int dzn_ = Tn_ / 3, dyn_ = Tn_ - 3 * dzn_;                              \
    const char* rn0 = xhb + (size_t)(((zb + dzn_) * 32) + (yc + dyn_)) * (XH_ROW*2);\
    const char* rn1 = rn0 + (XH_PLANE * 2);                                       \
    BPRE(Bc, 1, Bq1); LOADA(r0T, r1T, 2, Z);  MFMAG(X, Bq0);                      \
    BPRE(Bc, 2, Bq0); LOADA(r0T, r1T, 3, X);  MFMAG(Y, Bq1);                      \
    BPRE(Bc, 3, Bq1); LOADA(r0T, r1T, 4, Y);  MFMAG(Z, Bq0);                      \
    BPRE(Bc, 4, Bq0); LOADA(r0T, r1T, 5, Z);  MFMAG(X, Bq1);                      \
    BPRE(Bc, 5, Bq1); LOADA(r0T, r1T, 6, X);  MFMAG(Y, Bq0);                      \
    BPRE(Bc, 6, Bq0); if (T_ < 8) LOADA(rn0, rn1, 0, Y);  MFMAG(Z, Bq1);          \
    if (T_ < 8) LOADA(rn0, rn1, 1, Z);  MFMAG(X, Bq0);                            \
    if (T_ < 8) {                                                                 \
      asm volatile("s_waitcnt vmcnt(8)" ::: "memory");                            \
      __builtin_amdgcn_s_barrier();                                               \
    }                                                                             \
  }

  half8 A0[4], A1[4], A2[4], Bq0[5], Bq1[5];

  // prologue: stage tap 0, prefetch its first two A-groups, sync
  STAGE(0, 0);
  {
    const char* r0P = xhb + (size_t)((zb * 32) + yc) * (XH_ROW * 2);
    const char* r1P = r0P + (XH_PLANE * 2);
    LOADA(r0P, r1P, 0, A0);
    LOADA(r0P, r1P, 1, A1);
  }
  asm volatile("s_waitcnt vmcnt(8)" ::: "memory");   // staging done; A0,A1 in flight
  __builtin_amdgcn_s_barrier();

  #pragma unroll 1
  for (int s3 = 0; s3 < 9; s3 += 3) {   // A-buffer rotation period = 21 groups = 3 taps
    TAPBODY(s3 + 0, A0, A1, A2)
    TAPBODY(s3 + 1, A1, A2, A0)
    TAPBODY(s3 + 2, A2, A0, A1)
  }

#undef STAGE
#undef LOADA
#undef BPRE
#undef MFQ
#undef MFMAG
#undef TAPBODY

  // epilogue: D layout col(co)=lane&15, row(m=x)=q*4+reg; y>=30 waves are clamp-dupes
  if (y < 30) {
    #pragma unroll
    for (int cj = 0; cj < 5; ++cj) {
      const int co = cj * 16 + lx;
      if (co < NCH) {
        const float bv = bias[co];
        #pragma unroll
        for (int sz = 0; sz < 2; ++sz) {
          float* ob = out + ((size_t)(b * NCH + co) * 30 + (zb + sz)) * 900 + y * 30;
          #pragma unroll
          for (int s = 0; s < 2; ++s) {
            const int x0 = s * 16 + q * 4;
            const float4v v = acc[sz][s][cj];
            float2 p0; p0.x = v[0] + bv; p0.y = v[1] + bv;
            *(float2*)(ob + x0) = p0;
            if (x0 + 2 < 30) {
              float2 p1; p1.x = v[2] + bv; p1.y = v[3] + bv;
              *(float2*)(ob + x0 + 2) = p1;
            }
          }
        }
      }
    }
  }
}

extern "C" void kernel_launch(void* const* d_in, const int* in_sizes, int n_in,
                              void* d_out, int out_size, void* d_ws, size_t ws_size,
                              hipStream_t stream) {
  const float* x = (const float*)d_in[0];
  const float* w = (const float*)d_in[1];
  const float* bs[9];
  for (int i = 0; i < 9; ++i) bs[i] = (const float*)d_in[2 + i];
  float* ws  = (float*)d_ws;
  float* out = (float*)d_out;

  hipMemsetAsync(d_ws, 0, 144 * sizeof(float), stream);   // stats accumulators

  prepack_kernel<<<dim3(64, NBATCH), 256, 0, stream>>>(x, ws);
  build_half_kernel<<<(315 * 512 + 255) / 256, 256, 0, stream>>>(
      w, ws, bs[0], bs[1], bs[2], bs[3], bs[4], bs[5], bs[6], bs[7], bs[8]);
  conv_direct<<<dim3(960), 256, 71680, stream>>>(ws, out);
}

// Round 5
// 234.630 us; speedup vs baseline: 1.4644x; 1.0906x over previous
//
#include <hip/hip_runtime.h>
#include <hip/hip_fp16.h>
#include <math.h>

// Problem constants
#define NCH 72            // total channels (8*1 + 8*3 + 8*5)
#define SP  32768         // 32^3 spatial
#define NBATCH 8
#define NTOT (NBATCH*SP)  // per-channel element count = 262144

// ws layout (float offsets for the small stuff)
#define WS_SUMX   0       // 72
#define WS_SUMSQ  72      // 72
#define WS_SCALE  144     // 72 (unused now; kept for layout stability)
#define WS_BIAS   216     // 72
#define WS_K      288     // fp16 kernel matrix, fragment-blocked: 315 blocks * 1024 B

// byte offsets / strides for the packed fp16 x tensor
// NEW chunk-major row layout: [cc(10)][x-slot(34)][16B]; cc 0..8 = ci chunks of 8,
// cc 9 = zero chunk (k-pad). Row is still 5440 B = 2720 ushorts.
#define WS_XH_BYTES 323712          // 288*4 + 322560, 16B aligned
#define XH_ROW   2720               // ushorts per row (10 cc * 34 slots * 8)
#define XH_PLANE 87040              // 32 * XH_ROW
#define XH_BATCH 2785280            // 32 * XH_PLANE

typedef __attribute__((ext_vector_type(8))) _Float16 half8;
typedef __attribute__((ext_vector_type(4))) float float4v;
typedef __attribute__((ext_vector_type(4))) int int4v;

__device__ __forceinline__ void chmap(int c, int& f, int& m, int& d, int& dim) {
  if (c < 8)       { f = 0; m = c;          d = 0;          dim = 1; }
  else if (c < 32) { f = 1; m = (c - 8)/3;  d = (c - 8)%3;  dim = 3; }
  else             { f = 2; m = (c - 32)/5; d = (c - 32)%5; dim = 5; }
}

// ---------------- prepack: x -> fp16 chunk-major rows + fused BN stats ----------
// grid (64, 8): blockIdx.x = z*2 + half; block = half a z-plane (2 chunks of 256 pos)
__global__ __launch_bounds__(256) void prepack_kernel(const float* __restrict__ x,
                                                      float* __restrict__ ws) {
  __shared__ __align__(16) short tile[256 * 88];   // [pos(256)][ci(88 pad)] = 45 KB
  __shared__ float segS[72][3], segQ[72][3];
  const int t    = threadIdx.x;
  const int z    = blockIdx.x >> 1;
  const int half = blockIdx.x & 1;
  const int b    = blockIdx.y;
  ushort* xh = (ushort*)((char*)ws + WS_XH_BYTES);
  const float* xb = x + (size_t)b * NCH * SP + z * 1024 + half * 512;

  const int ci_s = t % 72, seg = t / 72;   // stats mapping (t < 216)
  float accS = 0.f, accQ = 0.f;

  for (int c = 0; c < 2; ++c) {
    if (c) __syncthreads();                 // protect tile reuse
    // phase 1: coalesced fp32 loads (fully unrolled), short4 LDS writes
    #pragma unroll
    for (int cig = 0; cig < 18; ++cig) {
      float v0 = xb[(size_t)(cig*4 + 0) * SP + c * 256 + t];
      float v1 = xb[(size_t)(cig*4 + 1) * SP + c * 256 + t];
      float v2 = xb[(size_t)(cig*4 + 2) * SP + c * 256 + t];
      float v3 = xb[(size_t)(cig*4 + 3) * SP + c * 256 + t];
      short s4[4] = { (short)__half_as_short(__float2half(v0)),
                      (short)__half_as_short(__float2half(v1)),
                      (short)__half_as_short(__float2half(v2)),
                      (short)__half_as_short(__float2half(v3)) };
      *(int2*)&tile[t * 88 + cig * 4] = *(const int2*)s4;   // 8B aligned
    }
    __syncthreads();
    // phase 2a: chunk-major writeout. Per cc (0..8): thread t writes its position's
    // 16B chunk to row (t>>5), slot (t&31): addr = row*2720 + cc*272 + slot*8 ushorts.
    // Lanes 0..31 are 512B-contiguous -> 8x512B segments per instruction.
    {
      ushort* gb = xh + (size_t)b * XH_BATCH + (size_t)(z * 32 + (half * 2 + c) * 8) * XH_ROW;
      #pragma unroll
      for (int j = 0; j < 9; ++j) {
        const int4v v = *(const int4v*)&tile[t * 88 + j * 8];
        *(int4v*)(gb + (size_t)(t >> 5) * XH_ROW + j * 272 + (t & 31) * 8) = v;
      }
      // zero chunk (cc=9): 8 rows x 34 slots = 272 chunks of 16B
      {
        const int4v zz = (int4v){0, 0, 0, 0};
        int idx = t;
        *(int4v*)(gb + (size_t)(idx / 34) * XH_ROW + 9 * 272 + (idx % 34) * 8) = zz;
        idx = 256 + t;
        if (idx < 272)
          *(int4v*)(gb + (size_t)(idx / 34) * XH_ROW + 9 * 272 + (idx % 34) * 8) = zz;
      }
    }
    // phase 2b: stats from the tile (per-ci column sums); unrolled for ds overlap
    if (seg < 3) {
      const int p0 = seg * 86;
      const int pn = (seg == 2) ? 84 : 86;
      #pragma unroll 4
      for (int i = 0; i < pn; ++i) {
        const float v = __half2float(__short_as_half(tile[(p0 + i) * 88 + ci_s]));
        accS += v; accQ += v * v;
      }
    }
  }
  if (seg < 3) { segS[ci_s][seg] = accS; segQ[ci_s][seg] = accQ; }
  __syncthreads();
  if (t < 144) {
    const int which = t / 72, ci = t % 72;
    const float v = which ? (segQ[ci][0] + segQ[ci][1] + segQ[ci][2])
                          : (segS[ci][0] + segS[ci][1] + segS[ci][2]);
    atomicAdd(&ws[(which ? WS_SUMSQ : WS_SUMX) + ci], v);
  }
}

// ---------------- build fp16 kernel matrix + (block 0) bias; scales computed inline ----
__global__ __launch_bounds__(256) void build_half_kernel(const float* __restrict__ weight,
    float* __restrict__ ws,
    const float* __restrict__ b00, const float* __restrict__ b01, const float* __restrict__ b02,
    const float* __restrict__ b10, const float* __restrict__ b11, const float* __restrict__ b12,
    const float* __restrict__ b20, const float* __restrict__ b21, const float* __restrict__ b22) {
  const int tid = blockIdx.x * 256 + threadIdx.x;
  const float invN = 1.0f / (float)NTOT;
  if (tid < 315 * 512) {
    const int blk = tid >> 9;
    const int e   = tid & 511;
    const int tap = blk / 35;
    const int r   = blk - tap * 35;
    const int kc  = r / 5, cj = r - (r / 5) * 5;
    const int l   = e >> 3, j = e & 7;
    const int co  = cj * 16 + (l & 15);
    const int kk  = kc * 32 + ((l >> 4) << 3) + j;
    short val = 0;
    if (co < NCH && kk < 216) {
      const int dx = kk / 72, ci = kk - dx * 72;
      int fi, u, dd, di; chmap(co, fi, u, dd, di);
      int fj, v, ee, dj; chmap(ci, fj, v, ee, dj);
      // chained selects (no runtime-indexed pointer array -> no scratch)
      const int s9 = fi * 3 + fj;
      const float* basis = b00;
      if (s9 == 1) basis = b01;
      if (s9 == 2) basis = b02;
      if (s9 == 3) basis = b10;
      if (s9 == 4) basis = b11;
      if (s9 == 5) basis = b12;
      if (s9 == 6) basis = b20;
      if (s9 == 7) basis = b21;
      if (s9 == 8) basis = b22;
      // inverse-std for input channel ci, computed from raw sums
      float norm;
      if (ci < 8) {
        float m = ws[WS_SUMX + ci] * invN;
        norm = ws[WS_SUMSQ + ci] * invN - m * m;
      } else if (ci < 32) {
        int m0 = 8 + ((ci - 8) / 3) * 3;
        norm = (ws[WS_SUMSQ+m0] + ws[WS_SUMSQ+m0+1] + ws[WS_SUMSQ+m0+2]) * invN;
      } else {
        int m0 = 32 + ((ci - 32) / 5) * 5;
        norm = (ws[WS_SUMSQ+m0] + ws[WS_SUMSQ+m0+1] + ws[WS_SUMSQ+m0+2]
              + ws[WS_SUMSQ+m0+3] + ws[WS_SUMSQ+m0+4]) * invN;
      }
      const float sc = 1.0f / sqrtf(norm + 1e-5f);
      const float* wp = weight + s9 * 128 + (u * 8 + v) * 2;
      const float w0 = wp[0] * sc, w1 = wp[1] * sc;
      const int t = tap * 3 + dx;
      const float f = w0 * basis[(dd * dj + ee) * 27 + t]
                    + w1 * basis[((di + dd) * dj + ee) * 27 + t];
      val = __half_as_short(__float2half(f));
    }
    ((short*)(ws + WS_K))[tid] = val;
  }
  // block 0: compute compensating bias (72 floats; nonzero only for scalar outputs)
  if (blockIdx.x == 0) {
    __shared__ float s_mean[8], s_scale[8];
    const int c = threadIdx.x;
    if (c < 8) {
      float m = ws[WS_SUMX + c] * invN;
      float norm = ws[WS_SUMSQ + c] * invN - m * m;
      s_mean[c]  = m;
      s_scale[c] = 1.0f / sqrtf(norm + 1e-5f);
    }
    __syncthreads();
    if (c < NCH) {
      float bia = 0.f;
      if (c < 8) {
        float id0 = 0.f, id1 = 0.f;
        #pragma unroll
        for (int t = 0; t < 27; ++t) { id0 += b00[t]; id1 += b00[27 + t]; }
        #pragma unroll
        for (int v = 0; v < 8; ++v) {
          float s  = s_scale[v];
          float w0 = weight[(c*8 + v)*2 + 0] * s;
          float w1 = weight[(c*8 + v)*2 + 1] * s;
          bia -= (w0 * id0 + w1 * id1) * s_mean[v];
        }
      }
      ws[WS_BIAS + c] = bia;
    }
  }
}

// ---------------- conv: 4-wave blocks, dbuf B in LDS, chunk-major A loads ------
// 960 blocks x 256 threads (4 y rows/block; y 30,31 clamp-duplicated). XCD r = batch.
// A-loads are now 4x256B lanes-contiguous segments (chunk-major layout) instead of
// 16x64B scatter: aoffb[kc] = cc*544 + dx*16 + lx*16 with g=kc*4+q, dx=g/9, cc=g%9
// (g==27 -> zero chunk cc=9). Tap pipeline unchanged from round 4.
__global__ __launch_bounds__(256, 2) void conv_direct(const float* __restrict__ ws,
                                                      float* __restrict__ out) {
  extern __shared__ __align__(16) char Bsm[];   // 2 x 35840 B (dynamic: 71680)

  const int lane = threadIdx.x & 63;
  const int wv   = threadIdx.x >> 6;   // 0..3: y sub-row
  const int lx   = lane & 15;
  const int q    = lane >> 4;
  const int i  = blockIdx.x;
  const int b  = i & 7;                // XCD-pinned batch
  const int q2 = i >> 3;               // 0..119
  const int yt = q2 & 7;               // 8 y-tiles of 4
  const int zp = q2 >> 3;              // 0..14
  const int y  = yt * 4 + wv;          // 0..31 (30,31 are clamp-duplicates)
  const int yc = (y > 29) ? 29 : y;    // clamped row for loads (keeps reads in-bounds)
  const int zb = zp * 2;

  const char* xhb = (const char*)ws + WS_XH_BYTES + (size_t)b * (XH_BATCH * 2);
  const char* Kb  = (const char*)(ws + WS_K);
  const float* __restrict__ bias = ws + WS_BIAS;

  const int lb16 = lane * 16;          // B-fragment: contiguous 1KB block + lane*16

  // per-kc A byte offset within a row (chunk-major): lanes of a q-group contiguous
  int aoffb[7];
  #pragma unroll
  for (int kc = 0; kc < 7; ++kc) {
    const int g = kc * 4 + q;
    aoffb[kc] = ((g >= 27) ? 9 * 544 : (g % 9) * 544 + (g / 9) * 16) + lx * 16;
  }

  float4v acc[2][2][5];
  #pragma unroll
  for (int sz = 0; sz < 2; ++sz)
    #pragma unroll
    for (int s = 0; s < 2; ++s)
      #pragma unroll
      for (int cj = 0; cj < 5; ++cj)
        acc[sz][s][cj] = (float4v){0.f, 0.f, 0.f, 0.f};

  // stage one tap's 35840 B into buffer BUF: 2240 x 16B chunks, thread t -> t + k*256.
#define STAGE(TAP, BUF) {                                                         \
    const char* src_ = Kb + (size_t)(TAP) * 35840;                                \
    char* dst_ = Bsm + (size_t)(BUF) * 35840;                                     \
    _Pragma("unroll")                                                             \
    for (int k = 0; k < 9; ++k) {                                                 \
      const int idx = (int)threadIdx.x + (k << 8);                                \
      if (idx < 2240) {                                                           \
        __builtin_amdgcn_global_load_lds(                                         \
          (const __attribute__((address_space(1))) void*)(src_ + (size_t)idx*16), \
          (__attribute__((address_space(3))) void*)(dst_ + ((k<<8) + (wv<<6))*16),\
          16, 0, 0);                                                              \
      }                                                                           \
    }                                                                             \
  }

#define LOADA(R0, R1, KC, A) {                                                    \
    const int ao_ = aoffb[KC];                                                    \
    A[0] = *(const half8*)((R0) + ao_);                                           \
    A[1] = *(const half8*)((R0) + ao_ + 256);                                     \
    A[2] = *(const half8*)((R1) + ao_);                                           \
    A[3] = *(const half8*)((R1) + ao_ + 256);                                     \
  }

#define BPRE(BC, KC, BQ) {                                                        \
    BQ[0] = *(const half8*)((BC) + ((KC)*5 + 0)*1024 + lb16);                     \
    BQ[1] = *(const half8*)((BC) + ((KC)*5 + 1)*1024 + lb16);                     \
    BQ[2] = *(const half8*)((BC) + ((KC)*5 + 2)*1024 + lb16);                     \
    BQ[3] = *(const half8*)((BC) + ((KC)*5 + 3)*1024 + lb16);                     \
    BQ[4] = *(const half8*)((BC) + ((KC)*5 + 4)*1024 + lb16);                     \
  }

#define MFQ(A, BF, CJ)                                                                         \
    acc[0][0][CJ] = __builtin_amdgcn_mfma_f32_16x16x32_f16(A[0], BF, acc[0][0][CJ], 0,0,0);    \
    acc[0][1][CJ] = __builtin_amdgcn_mfma_f32_16x16x32_f16(A[1], BF, acc[0][1][CJ], 0,0,0);    \
    acc[1][0][CJ] = __builtin_amdgcn_mfma_f32_16x16x32_f16(A[2], BF, acc[1][0][CJ], 0,0,0);    \
    acc[1][1][CJ] = __builtin_amdgcn_mfma_f32_16x16x32_f16(A[3], BF, acc[1][1][CJ], 0,0,0);

#define MFMAG(A, BQ) {                                                            \
    __builtin_amdgcn_s_setprio(1);                                                \
    MFQ(A, BQ[0], 0) MFQ(A, BQ[1], 1) MFQ(A, BQ[2], 2) MFQ(A, BQ[3], 3) MFQ(A, BQ[4], 4) \
    __builtin_amdgcn_s_setprio(0);                                                \
  }

  // One tap: entering with X=A(T,0), Y=A(T,1) in flight and Bsm[T&1] staged+visible.
#define TAPBODY(TT, X, Y, Z) {                                                    \
    const int T_  = (TT);                                                         \
    const int dz_ = T_ / 3, dy_ = T_ - 3 * dz_;                                   \
    const char* r0T = xhb + (size_t)(((zb + dz_) * 32) + (yc + dy_)) * (XH_ROW*2);\
    const char* r1T = r0T + (XH_PLANE * 2);                                       \
    const char* Bc  = Bsm + (size_t)(T_ & 1) * 35840;                             \
    BPRE(Bc, 0, Bq0);                                                             \
    if (T_ < 8) STAGE(T_ + 1, ((T_ + 1) & 1));                                    \
    const int Tn_  = (T_ < 8) ? T_ + 1 : T_;                                      \
    const int dzn_ = Tn_ / 3, dyn_ = Tn_ - 3 * dzn_;                              \
    const char* rn0 = xhb + (size_t)(((zb + dzn_) * 32) + (yc + dyn_)) * (XH_ROW*2);\
    const char* rn1 = rn0 + (XH_PLANE * 2);                                       \
    BPRE(Bc, 1, Bq1); LOADA(r0T, r1T, 2, Z);  MFMAG(X, Bq0);                      \
    BPRE(Bc, 2, Bq0); LOADA(r0T, r1T, 3, X);  MFMAG(Y, Bq1);                      \
    BPRE(Bc, 3, Bq1); LOADA(r0T, r1T, 4, Y);  MFMAG(Z, Bq0);                      \
    BPRE(Bc, 4, Bq0); LOADA(r0T, r1T, 5, Z);  MFMAG(X, Bq1);                      \
    BPRE(Bc, 5, Bq1); LOADA(r0T, r1T, 6, X);  MFMAG(Y, Bq0);                      \
    BPRE(Bc, 6, Bq0); if (T_ < 8) LOADA(rn0, rn1, 0, Y);  MFMAG(Z, Bq1);          \
    if (T_ < 8) LOADA(rn0, rn1, 1, Z);  MFMAG(X, Bq0);                            \
    if (T_ < 8) {                                                                 \
      asm volatile("s_waitcnt vmcnt(8)" ::: "memory");                            \
      __builtin_amdgcn_s_barrier();                                               \
    }                                                                             \
  }

  half8 A0[4], A1[4], A2[4], Bq0[5], Bq1[5];

  // prologue: stage tap 0, prefetch its first two A-groups, sync
  STAGE(0, 0);
  {
    const char* r0P = xhb + (size_t)((zb * 32) + yc) * (XH_ROW * 2);
    const char* r1P = r0P + (XH_PLANE * 2);
    LOADA(r0P, r1P, 0, A0);
    LOADA(r0P, r1P, 1, A1);
  }
  asm volatile("s_waitcnt vmcnt(8)" ::: "memory");   // staging done; A0,A1 in flight
  __builtin_amdgcn_s_barrier();

  #pragma unroll 1
  for (int s3 = 0; s3 < 9; s3 += 3) {   // A-buffer rotation period = 21 groups = 3 taps
    TAPBODY(s3 + 0, A0, A1, A2)
    TAPBODY(s3 + 1, A1, A2, A0)
    TAPBODY(s3 + 2, A2, A0, A1)
  }

#undef STAGE
#undef LOADA
#undef BPRE
#undef MFQ
#undef MFMAG
#undef TAPBODY

  // epilogue: D layout col(co)=lane&15, row(m=x)=q*4+reg; y>=30 waves are clamp-dupes
  if (y < 30) {
    #pragma unroll
    for (int cj = 0; cj < 5; ++cj) {
      const int co = cj * 16 + lx;
      if (co < NCH) {
        const float bv = bias[co];
        #pragma unroll
        for (int sz = 0; sz < 2; ++sz) {
          float* ob = out + ((size_t)(b * NCH + co) * 30 + (zb + sz)) * 900 + y * 30;
          #pragma unroll
          for (int s = 0; s < 2; ++s) {
            const int x0 = s * 16 + q * 4;
            const float4v v = acc[sz][s][cj];
            float2 p0; p0.x = v[0] + bv; p0.y = v[1] + bv;
            *(float2*)(ob + x0) = p0;
            if (x0 + 2 < 30) {
              float2 p1; p1.x = v[2] + bv; p1.y = v[3] + bv;
              *(float2*)(ob + x0 + 2) = p1;
            }
          }
        }
      }
    }
  }
}

extern "C" void kernel_launch(void* const* d_in, const int* in_sizes, int n_in,
                              void* d_out, int out_size, void* d_ws, size_t ws_size,
                              hipStream_t stream) {
  const float* x = (const float*)d_in[0];
  const float* w = (const float*)d_in[1];
  const float* bs[9];
  for (int i = 0; i < 9; ++i) bs[i] = (const float*)d_in[2 + i];
  float* ws  = (float*)d_ws;
  float* out = (float*)d_out;

  hipMemsetAsync(d_ws, 0, 144 * sizeof(float), stream);   // stats accumulators

  prepack_kernel<<<dim3(64, NBATCH), 256, 0, stream>>>(x, ws);
  build_half_kernel<<<(315 * 512 + 255) / 256, 256, 0, stream>>>(
      w, ws, bs[0], bs[1], bs[2], bs[3], bs[4], bs[5], bs[6], bs[7], bs[8]);
  conv_direct<<<dim3(960), 256, 71680, stream>>>(ws, out);
}